// Round 5
// baseline (650.734 us; speedup 1.0000x reference)
//
#include <hip/hip_runtime.h>

#define T_ 512
#define K_ 128
#define B_ 256
#define NEGINF (-3.4028235e38f)

// 512 blocks x 512 threads (8 waves). role = blockIdx&1: 0=forward, 1=viterbi.
// Lane layout (both roles): p = tid&63 -> columns {p, p+64}; cc = tid>>6 (wave id)
// -> i-slice [cc*16, cc*16+16). Slice reads are wave-uniform broadcasts.
// Phase A: per-lane partial over its slice -> LDS partials.
// Phase B (tid<128): combine 8 partials per column, +emit, write new vector.
// W slice = 32 named registers + asm fence (r1-r3: plain arrays never reg-allocated).
// LDS ~77.5KB/block -> 2 blocks/CU (one fwd + one vit pairs fwd's light steps
// with vit's heavy ones and hides barrier latency).

#define GR(F) F(0) F(1) F(2) F(3)

#define DECLW(g) float wa##g##0, wa##g##1, wa##g##2, wa##g##3, \
                       wb##g##0, wb##g##1, wb##g##2, wb##g##3;
#define LOADW(g) wa##g##0 = wp[(4*g+0)*K_];      wa##g##1 = wp[(4*g+1)*K_]; \
                 wa##g##2 = wp[(4*g+2)*K_];      wa##g##3 = wp[(4*g+3)*K_]; \
                 wb##g##0 = wp[(4*g+0)*K_ + 64]; wb##g##1 = wp[(4*g+1)*K_ + 64]; \
                 wb##g##2 = wp[(4*g+2)*K_ + 64]; wb##g##3 = wp[(4*g+3)*K_ + 64];
#define EXPW(g)  wa##g##0 = __expf(wa##g##0); wa##g##1 = __expf(wa##g##1); \
                 wa##g##2 = __expf(wa##g##2); wa##g##3 = __expf(wa##g##3); \
                 wb##g##0 = __expf(wb##g##0); wb##g##1 = __expf(wb##g##1); \
                 wb##g##2 = __expf(wb##g##2); wb##g##3 = __expf(wb##g##3);
#define FENCEW(g) asm volatile("" : "+v"(wa##g##0), "+v"(wa##g##1), "+v"(wa##g##2), "+v"(wa##g##3), \
                                    "+v"(wb##g##0), "+v"(wb##g##1), "+v"(wb##g##2), "+v"(wb##g##3));

#define VSTEP(val, wreg, idx, mm, aa) \
    { float s_ = (val) + (wreg); if (s_ > (mm)) { (mm) = s_; (aa) = (idx); } }

__global__ __launch_bounds__(512, 4) void crf_main(
    const float* __restrict__ emissions,
    const int* __restrict__ tag_ids,
    const int* __restrict__ lengths,
    const float* __restrict__ transitions,
    float* __restrict__ out,
    float* __restrict__ ws_ll,
    int* __restrict__ ws_cnt)
{
    __shared__ __align__(16) unsigned char smem[77392];
    unsigned char* bp   = smem;                              // [T_*K_] (vit)
    float* part = (float*)(smem + 65536);                    // vit [128][20] / fwd [128][12]
    float* buf  = (float*)(smem + 65536 + 10240);            // [2][128] alpha-exp / viterbi
    unsigned char* dec = smem + 65536 + 10240 + 1024;        // [T_]
    float* sNorm = (float*)(dec + T_);                       // [2]
    float* redS  = sNorm + 2;                                // [8]
    int*   redI  = (int*)(redS + 8);                         // [8]
    int*   ltag  = redI + 8;                                 // [1]

    const int bx   = blockIdx.x;
    const int b    = bx >> 1;
    const int role = bx & 1;
    const int tid  = threadIdx.x;
    const int len  = lengths[b];
    const float* emB = emissions + (size_t)b * T_ * K_;
    const int*  tagB = tag_ids + b * T_;

    const int p  = tid & 63;            // column base (cols p, p+64)
    const int cc = tid >> 6;            // wave id = i-slice index

    GR(DECLW)
    {
        const float* wp = transitions + (cc * 16) * K_ + p;
        GR(LOADW)
        if (role == 0) { GR(EXPW) }
        GR(FENCEW)
    }

    float emNext = 0.f;
    if (tid < K_) emNext = emB[K_ + tid];                    // prefetch t=1 for phase B

    if (role == 0) {
        // ---------- sequence score (unary+binary), one t per thread ----------
        {
            float s = 0.f;
            if (tid < len) {
                int tg = tagB[tid];
                s = emB[tid * K_ + tg];
                if (tid >= 1) s += transitions[tagB[tid - 1] * K_ + tg];
            }
            #pragma unroll
            for (int m = 1; m < 64; m <<= 1) s += __shfl_xor(s, m);
            if ((tid & 63) == 0) redS[tid >> 6] = s;
        }
        // ---------- init t=0 ----------
        if (tid < K_) buf[tid] = __expf(emB[tid]);           // offset S = 0
        if (tid == 0) sNorm[0] = emB[0];
        __syncthreads();

        int cur = 0;
        float Sprev = 0.f;
        for (int t = 1; t < len; ++t) {
            // phase A: wave-uniform slice broadcast + 2 dots
            const float* ea = &buf[cur * K_ + cc * 16];
            float4 e0 = *(const float4*)(ea);
            float4 e1 = *(const float4*)(ea + 4);
            float4 e2 = *(const float4*)(ea + 8);
            float4 e3 = *(const float4*)(ea + 12);
            float d0 = 0.f, d1 = 0.f;
#define FDOT(v4, g) d0 = fmaf(v4.x, wa##g##0, d0); d0 = fmaf(v4.y, wa##g##1, d0); \
                    d0 = fmaf(v4.z, wa##g##2, d0); d0 = fmaf(v4.w, wa##g##3, d0); \
                    d1 = fmaf(v4.x, wb##g##0, d1); d1 = fmaf(v4.y, wb##g##1, d1); \
                    d1 = fmaf(v4.z, wb##g##2, d1); d1 = fmaf(v4.w, wb##g##3, d1);
            FDOT(e0, 0) FDOT(e1, 1) FDOT(e2, 2) FDOT(e3, 3)
            part[p * 12 + cc]        = d0;
            part[(p + 64) * 12 + cc] = d1;
            float emit = emNext;
            if (tid < K_) { int tn = (t + 1 < T_) ? t + 1 : T_ - 1;
                            emNext = emB[tn * K_ + tid]; }
            __syncthreads();
            // phase B: combine 8 partials, log, renorm, write
            if (tid < K_) {
                float4 q0 = *(const float4*)&part[tid * 12];
                float4 q1 = *(const float4*)&part[tid * 12 + 4];
                float sum = ((q0.x + q0.y) + (q0.z + q0.w))
                          + ((q1.x + q1.y) + (q1.z + q1.w));
                float Scur = sNorm[cur];
                float anew = __logf(sum) + Sprev + emit;
                buf[(cur ^ 1) * K_ + tid] = __expf(anew - Scur);
                if (tid == 0) sNorm[cur ^ 1] = anew;
                Sprev = Scur;
            }
            cur ^= 1;
            __syncthreads();
        }
        // ---------- logZ + ws_ll ----------
        float logZv = 0.f;
        if (tid < 64) {
            float s = buf[cur * K_ + tid] + buf[cur * K_ + tid + 64];
            #pragma unroll
            for (int m = 1; m < 64; m <<= 1) s += __shfl_xor(s, m);
            logZv = Sprev + __logf(s);                       // lane 0 valid
        }
        if (tid == 0) {
            float sc = 0.f;
            #pragma unroll
            for (int w = 0; w < 8; ++w) sc += redS[w];
            ws_ll[b] = sc - logZv;
        }
    } else {
        // ================= viterbi block =================
        if (tid < K_) buf[tid] = emB[tid];
        __syncthreads();

        int cur = 0;
        for (int t = 1; t < len; ++t) {
            // phase A: slice broadcast + blocked max/argmax for 2 columns
            const float* va = &buf[cur * K_ + cc * 16];
            float4 e0 = *(const float4*)(va);
            float4 e1 = *(const float4*)(va + 4);
            float4 e2 = *(const float4*)(va + 8);
            float4 e3 = *(const float4*)(va + 12);
            // column p: halves k=0..7 / k=8..15 (strict >, ascending = first-max)
            float ma0 = NEGINF, ma1 = NEGINF; int aa0 = 0, aa1 = 0;
            VSTEP(e0.x, wa00, 0, ma0, aa0)  VSTEP(e0.y, wa01, 1, ma0, aa0)
            VSTEP(e0.z, wa02, 2, ma0, aa0)  VSTEP(e0.w, wa03, 3, ma0, aa0)
            VSTEP(e1.x, wa10, 4, ma0, aa0)  VSTEP(e1.y, wa11, 5, ma0, aa0)
            VSTEP(e1.z, wa12, 6, ma0, aa0)  VSTEP(e1.w, wa13, 7, ma0, aa0)
            VSTEP(e2.x, wa20, 8, ma1, aa1)  VSTEP(e2.y, wa21, 9, ma1, aa1)
            VSTEP(e2.z, wa22,10, ma1, aa1)  VSTEP(e2.w, wa23,11, ma1, aa1)
            VSTEP(e3.x, wa30,12, ma1, aa1)  VSTEP(e3.y, wa31,13, ma1, aa1)
            VSTEP(e3.z, wa32,14, ma1, aa1)  VSTEP(e3.w, wa33,15, ma1, aa1)
            if (ma1 > ma0) { ma0 = ma1; aa0 = aa1; }
            // column p+64
            float mb0 = NEGINF, mb1 = NEGINF; int ab0 = 0, ab1 = 0;
            VSTEP(e0.x, wb00, 0, mb0, ab0)  VSTEP(e0.y, wb01, 1, mb0, ab0)
            VSTEP(e0.z, wb02, 2, mb0, ab0)  VSTEP(e0.w, wb03, 3, mb0, ab0)
            VSTEP(e1.x, wb10, 4, mb0, ab0)  VSTEP(e1.y, wb11, 5, mb0, ab0)
            VSTEP(e1.z, wb12, 6, mb0, ab0)  VSTEP(e1.w, wb13, 7, mb0, ab0)
            VSTEP(e2.x, wb20, 8, mb1, ab1)  VSTEP(e2.y, wb21, 9, mb1, ab1)
            VSTEP(e2.z, wb22,10, mb1, ab1)  VSTEP(e2.w, wb23,11, mb1, ab1)
            VSTEP(e3.x, wb30,12, mb1, ab1)  VSTEP(e3.y, wb31,13, mb1, ab1)
            VSTEP(e3.z, wb32,14, mb1, ab1)  VSTEP(e3.w, wb33,15, mb1, ab1)
            if (mb1 > mb0) { mb0 = mb1; ab0 = ab1; }
            *(float2*)&part[p * 20 + 2 * cc] =
                make_float2(ma0, (float)(aa0 + cc * 16));
            *(float2*)&part[(p + 64) * 20 + 2 * cc] =
                make_float2(mb0, (float)(ab0 + cc * 16));
            float emit = emNext;
            if (tid < K_) { int tn = (t + 1 < T_) ? t + 1 : T_ - 1;
                            emNext = emB[tn * K_ + tid]; }
            __syncthreads();
            // phase B: merge 8 partials ascending (strict > keeps first max)
            if (tid < K_) {
                const float* pr = &part[tid * 20];
                float4 r0 = *(const float4*)(pr);
                float4 r1 = *(const float4*)(pr + 4);
                float4 r2 = *(const float4*)(pr + 8);
                float4 r3 = *(const float4*)(pr + 12);
                float bm = r0.x; float ba = r0.y;
                if (r0.z > bm) { bm = r0.z; ba = r0.w; }
                if (r1.x > bm) { bm = r1.x; ba = r1.y; }
                if (r1.z > bm) { bm = r1.z; ba = r1.w; }
                if (r2.x > bm) { bm = r2.x; ba = r2.y; }
                if (r2.z > bm) { bm = r2.z; ba = r2.w; }
                if (r3.x > bm) { bm = r3.x; ba = r3.y; }
                if (r3.z > bm) { bm = r3.z; ba = r3.w; }
                buf[(cur ^ 1) * K_ + tid] = bm + emit;
                bp[t * K_ + tid] = (unsigned char)(int)ba;
            }
            cur ^= 1;
            __syncthreads();
        }
        // ---------- last tag: argmax (first-max-wins) ----------
        if (tid < 64) {
            float m = buf[cur * K_ + tid]; int a = tid;
            float v2 = buf[cur * K_ + tid + 64];
            if (v2 > m) { m = v2; a = tid + 64; }
            #pragma unroll
            for (int s = 1; s < 64; s <<= 1) {
                float om = __shfl_xor(m, s);
                int   oa = __shfl_xor(a, s);
                if (om > m || (om == m && oa < a)) { m = om; a = oa; }
            }
            if (tid == 0) *ltag = a;
        }
        __syncthreads();
        // ---------- backtrace ----------
        if (tid == 0) {
            int tg = *ltag;
            for (int t = T_ - 1; t >= 1; --t) {
                dec[t] = (unsigned char)tg;
                if (t < len) tg = bp[t * K_ + tg];           // identity for t >= len
            }
            dec[0] = (unsigned char)tg;
        }
        __syncthreads();
        // ---------- decoded write + accuracy ----------
        {
            int dv = dec[tid];
            out[1 + b * T_ + tid] = (float)dv;
            int good = (tid < len && tagB[tid] == dv) ? 1 : 0;
            #pragma unroll
            for (int m = 1; m < 64; m <<= 1) good += __shfl_xor(good, m);
            if ((tid & 63) == 0) redI[tid >> 6] = good;
        }
        __syncthreads();
        if (tid == 0) {
            int cnt = 0;
            #pragma unroll
            for (int w = 0; w < 8; ++w) cnt += redI[w];
            ws_cnt[b] = cnt;
        }
    }
}

// loss = -mean(ll), accuracy = sum(correct)/sum(len)
__global__ void crf_final(const float* __restrict__ ws_ll,
                          const int* __restrict__ ws_cnt,
                          const int* __restrict__ lengths,
                          float* __restrict__ out)
{
    __shared__ float sll[4];
    __shared__ int scnt[4], slen[4];
    int tid = threadIdx.x;                                   // blockDim == 256
    float ll = ws_ll[tid];
    int   cn = ws_cnt[tid];
    int   L  = lengths[tid];
    #pragma unroll
    for (int m = 1; m < 64; m <<= 1) {
        ll += __shfl_xor(ll, m);
        cn += __shfl_xor(cn, m);
        L  += __shfl_xor(L, m);
    }
    if ((tid & 63) == 0) { sll[tid >> 6] = ll; scnt[tid >> 6] = cn; slen[tid >> 6] = L; }
    __syncthreads();
    if (tid == 0) {
        float llS = sll[0] + sll[1] + sll[2] + sll[3];
        int   cS  = scnt[0] + scnt[1] + scnt[2] + scnt[3];
        int   LS  = slen[0] + slen[1] + slen[2] + slen[3];
        out[0] = -llS / (float)B_;
        out[1 + B_ * T_] = (float)cS / (float)LS;
    }
}

extern "C" void kernel_launch(void* const* d_in, const int* in_sizes, int n_in,
                              void* d_out, int out_size, void* d_ws, size_t ws_size,
                              hipStream_t stream) {
    const float* emissions   = (const float*)d_in[0];
    const int*   tag_ids     = (const int*)d_in[1];
    const int*   lengths     = (const int*)d_in[2];
    const float* transitions = (const float*)d_in[3];
    float* out = (float*)d_out;

    float* ws_ll  = (float*)d_ws;
    int*   ws_cnt = (int*)((char*)d_ws + B_ * sizeof(float));

    crf_main<<<2 * B_, 512, 0, stream>>>(emissions, tag_ids, lengths, transitions,
                                         out, ws_ll, ws_cnt);
    crf_final<<<1, B_, 0, stream>>>(ws_ll, ws_cnt, lengths, out);
}